// Round 14
// baseline (8498.249 us; speedup 1.0000x reference)
//
#include <hip/hip_runtime.h>
#include <hip/hip_bf16.h>

// LSTM: L=1024, B=64, I=512, H=512, fp32 in/out.
// Persistent kernel, 256 WGs x 256 thr (1 WG/CU). 8 clusters x 32 WGs;
// cluster = 8 batches; wave = 16 gate rows (4 h-idx x 4 gates). Weights in
// VGPRs as MFMA B-fragments; C state in registers; x-GEMM in-loop (overlaps
// producer lag and paces the poll — round-11 lesson).
// ROUND-14 = ROUND-13 (flagless fused detect+load, parity-authoritative)
// + FAT COALESCED h-STORES (the missing prerequisite round 13 exposed):
//   after the elementwise, an intra-wave LDS transpose (4 ds_write_b16 per
//   active lane -> 8B contiguous per batch, same wave, in-order DS, no
//   barrier) lets lanes 0..7 publish the wave's 64B payload as 8 dwordx2
//   stores (was 32 scattered 2B): 4x fewer transactions, 4x coverage each.
//   Producer landing tail = slowest-of-1024 fat stores (was 4096 tiny);
//   consumer's first UNPACED fused load+parity-check then hits -> the step
//   pays ONE MALL RT instead of round-8's two (flag RT + data RT).
// Parity code: code = h_bits ^ (((t>>1)&1)?0xFFFF:0); |h|<=1 => bf16
// bit14==0, so coded parity-1 => bit14==1. Validator tests bit14 only.
// Slot-reuse safety (no flags): producer stores h(t) only after validating
// ALL of h(t-1); every wave stored h(t-1) only after reading h(t-2)
// (program order) => slot t&1 == (t-2)&1 is no longer being read.
// Init/stale safety: hx memset 0x7F each launch (u16 0x7F7F: bit14=1 fails
// the parity-0 check used by t=1/t=2 readers, the only ones who can see
// init data); within-launch staleness fails the alternating parity;
// cross-replay staleness erased by the memset. (Proven rounds 10/13.)

typedef __attribute__((ext_vector_type(8))) short bf16x8;
typedef __attribute__((ext_vector_type(4))) float f32x4;

#define NT 1024
#define NB 64
#define NH 512
#define NI 512

#define HX_BYTES (2 * NB * NH * 2)    // 128 KiB double buffer

#define VBITS 0x4000400040004000ULL   // bit14 of each u16 lane

__device__ __forceinline__ bf16x8 pack8(float4 a, float4 b) {
    union U2 { __hip_bfloat162 h; unsigned int u; } c0, c1, c2, c3;
    c0.h = __float22bfloat162_rn(make_float2(a.x, a.y));
    c1.h = __float22bfloat162_rn(make_float2(a.z, a.w));
    c2.h = __float22bfloat162_rn(make_float2(b.x, b.y));
    c3.h = __float22bfloat162_rn(make_float2(b.z, b.w));
    union R { bf16x8 v; unsigned int u[4]; } r;
    r.u[0] = c0.u; r.u[1] = c1.u; r.u[2] = c2.u; r.u[3] = c3.u;
    return r.v;
}

__device__ __forceinline__ float sigm(float v) {
    return 1.0f / (1.0f + __expf(-v));
}
__device__ __forceinline__ float tanh_f(float v) {
    float e = __expf(-2.0f * fabsf(v));        // in (0,1], no overflow
    float r = (1.0f - e) / (1.0f + e);         // <= 1 in fp32
    return copysignf(r, v);
}

__global__ __launch_bounds__(256, 1) void lstm_fused(
    const float* __restrict__ x,
    const float* __restrict__ h0,
    const float* __restrict__ c0,
    const float* __restrict__ Wf, const float* __restrict__ Bf,
    const float* __restrict__ Wi, const float* __restrict__ Bi,
    const float* __restrict__ Wc, const float* __restrict__ Bc,
    const float* __restrict__ Wo, const float* __restrict__ Bo,
    float* __restrict__ out,
    unsigned short* __restrict__ hx)
{
    // per-wave 64B transpose tile: [wave][batch(8)][jjoff(4)] u16
    __shared__ unsigned short xch[4][8][4];

    const int tid  = threadIdx.x;
    const int wv   = tid >> 6;            // wave 0..3
    const int lane = tid & 63;
    const int n    = lane & 15;           // D col (gate row within wave tile)
    const int kg   = lane >> 4;           // k-group 0..3
    const int cl   = blockIdx.x & 7;      // cluster (XCD-swizzle heuristic)
    const int wg   = blockIdx.x >> 3;     // WG within cluster, 0..31

    const int jj = (wv << 2) + (n >> 2);          // 0..15 within WG
    const int j  = (wg << 4) + jj;                // global h index
    const int g  = n & 3;                         // 0=f 1=i 2=c 3=o

    const float* Wg = (g == 0) ? Wf : (g == 1) ? Wi : (g == 2) ? Wc : Wo;
    const float* Bg = (g == 0) ? Bf : (g == 1) ? Bi : (g == 2) ? Bc : Bo;

    const int m_a   = (n < 8) ? n : 7;            // A-row batch (8..15 dup)
    const int bglob = cl * 8 + m_a;

    // ---- prologue: static B-fragments (weights, bf16) into VGPRs ----
    bf16x8 bfrag[32];                             // [0..15]=h-part, [16..31]=x
    {
        const float* wrow = Wg + (size_t)j * (NH + NI);
        #pragma unroll
        for (int kb = 0; kb < 32; ++kb) {
            const float* p = wrow + kb * 32 + kg * 8;
            bfrag[kb] = pack8(*(const float4*)(p), *(const float4*)(p + 4));
        }
    }
    const float bias_v = Bg[j];

    const bool active = (g == 0) && (kg < 2);     // 8 lanes/wave x 4 regs
    float Cst[4];
    #pragma unroll
    for (int r = 0; r < 4; ++r)
        Cst[r] = active ? c0[(size_t)(cl * 8 + kg * 4 + r) * NH + j] : 0.0f;

    const int jbase = (wg << 4) + (wv << 2);      // first of this wave's 4 j
    const int jjoff = n >> 2;                     // 0..3 (active lanes)

    for (int t = 0; t < NT; ++t) {
        // -- x fragments + x-partial MFMAs (overlap producer lag; pacing) --
        const float* xrow = x + ((size_t)t * NB + bglob) * NI;
        bf16x8 xfrag[16];
        #pragma unroll
        for (int q = 0; q < 16; ++q) {
            const float* p = xrow + q * 32 + kg * 8;
            xfrag[q] = pack8(*(const float4*)(p), *(const float4*)(p + 4));
        }
        f32x4 a0 = {bias_v, bias_v, bias_v, bias_v};
        f32x4 a1 = {0.f, 0.f, 0.f, 0.f};
        f32x4 a2 = {0.f, 0.f, 0.f, 0.f};
        f32x4 a3 = {0.f, 0.f, 0.f, 0.f};
        #pragma unroll
        for (int q = 0; q < 16; q += 4) {
            a0 = __builtin_amdgcn_mfma_f32_16x16x32_bf16(xfrag[q],     bfrag[16 + q],     a0, 0, 0, 0);
            a1 = __builtin_amdgcn_mfma_f32_16x16x32_bf16(xfrag[q + 1], bfrag[16 + q + 1], a1, 0, 0, 0);
            a2 = __builtin_amdgcn_mfma_f32_16x16x32_bf16(xfrag[q + 2], bfrag[16 + q + 2], a2, 0, 0, 0);
            a3 = __builtin_amdgcn_mfma_f32_16x16x32_bf16(xfrag[q + 3], bfrag[16 + q + 3], a3, 0, 0, 0);
        }

        // -- h fragments: FUSED poll+load (parity authoritative, no flags) --
        bf16x8 hfrag[16];
        if (t == 0) {
            const float* hrow = h0 + (size_t)bglob * NH;
            #pragma unroll
            for (int q = 0; q < 16; ++q) {
                const float* p = hrow + q * 32 + kg * 8;
                hfrag[q] = pack8(*(const float4*)(p), *(const float4*)(p + 4));
            }
        } else {
            const unsigned long long pm64 =
                (((t - 1) >> 1) & 1) ? ~0ULL : 0ULL;
            const unsigned short* hrow =
                hx + ((size_t)((t - 1) & 1) * NB + bglob) * NH;
            int attempt = 0;
            for (;;) {
                unsigned long long accb = 0;
                #pragma unroll
                for (int q = 0; q < 16; ++q) {
                    const unsigned long long* p =
                        (const unsigned long long*)(hrow + q * 32 + kg * 8);
                    union { bf16x8 v; unsigned long long u[2]; } un;
                    unsigned long long w0 = __hip_atomic_load(
                        p, __ATOMIC_RELAXED, __HIP_MEMORY_SCOPE_AGENT) ^ pm64;
                    unsigned long long w1 = __hip_atomic_load(
                        p + 1, __ATOMIC_RELAXED, __HIP_MEMORY_SCOPE_AGENT) ^ pm64;
                    accb |= w0;
                    accb |= w1;
                    un.u[0] = w0;
                    un.u[1] = w1;
                    hfrag[q] = un.v;
                }
                if (__all((accb & VBITS) == 0ULL)) break;   // valid => in regs
                if (++attempt > (1 << 14)) break;           // hang safety
                __builtin_amdgcn_s_sleep(4);                // paced retry
            }
            __builtin_amdgcn_sched_barrier(0);
        }

        #pragma unroll
        for (int q = 0; q < 16; q += 4) {
            a0 = __builtin_amdgcn_mfma_f32_16x16x32_bf16(hfrag[q],     bfrag[q],     a0, 0, 0, 0);
            a1 = __builtin_amdgcn_mfma_f32_16x16x32_bf16(hfrag[q + 1], bfrag[q + 1], a1, 0, 0, 0);
            a2 = __builtin_amdgcn_mfma_f32_16x16x32_bf16(hfrag[q + 2], bfrag[q + 2], a2, 0, 0, 0);
            a3 = __builtin_amdgcn_mfma_f32_16x16x32_bf16(hfrag[q + 3], bfrag[q + 3], a3, 0, 0, 0);
        }
        f32x4 acc = (a0 + a1) + (a2 + a3);

        // -- gather f/i/c/o in 4-lane groups, elementwise, code, transpose --
        const unsigned int pmask = ((t >> 1) & 1) ? 0xFFFFu : 0u;
        float harr[4];
        #pragma unroll
        for (int r = 0; r < 4; ++r) {
            float fv = acc[r];
            float iv = __shfl_xor(fv, 1);
            float gv = __shfl_xor(fv, 2);
            float ov = __shfl_xor(fv, 3);
            if (active) {
                float ft = sigm(fv);
                float it = sigm(iv);
                float gt = tanh_f(gv);
                float ot = sigm(ov);
                float Cn = ft * Cst[r] + it * gt;
                Cst[r] = Cn;
                float ht = ot * tanh_f(Cn);       // |ht| <= 1.0 in fp32
                harr[r] = ht;
                __hip_bfloat16 hb = __float2bfloat16(ht);
                // transpose via LDS: batch kg*4+r, column jjoff (in-wave,
                // DS ops are in-order within a wave; no barrier needed)
                xch[wv][kg * 4 + r][jjoff] =
                    (unsigned short)((*(unsigned short*)&hb) ^ pmask);
            }
        }

        // -- publish: lanes 0..7 store one batch's 4 coded j's as dwordx2 --
        if (lane < 8) {
            unsigned long long v = *(const unsigned long long*)xch[wv][lane];
            unsigned long long* dst = (unsigned long long*)
                (hx + (size_t)(t & 1) * NB * NH
                    + (size_t)(cl * 8 + lane) * NH + jbase);
            __hip_atomic_store(dst, v, __ATOMIC_RELAXED,
                               __HIP_MEMORY_SCOPE_AGENT);
        }

        // -- fp32 output stores AFTER h publish (off the critical path) --
        if (active) {
            #pragma unroll
            for (int r = 0; r < 4; ++r) {
                int m = kg * 4 + r;
                out[((size_t)t * NB + cl * 8 + m) * NH + j] = harr[r];
            }
        }
    }
}

extern "C" void kernel_launch(void* const* d_in, const int* in_sizes, int n_in,
                              void* d_out, int out_size, void* d_ws, size_t ws_size,
                              hipStream_t stream) {
    const float* x  = (const float*)d_in[0];
    const float* h0 = (const float*)d_in[1];
    const float* c0 = (const float*)d_in[2];
    const float* Wf = (const float*)d_in[3];
    const float* Bf = (const float*)d_in[4];
    const float* Wi = (const float*)d_in[5];
    const float* Bi = (const float*)d_in[6];
    const float* Wc = (const float*)d_in[7];
    const float* Bc = (const float*)d_in[8];
    const float* Wo = (const float*)d_in[9];
    const float* Bo = (const float*)d_in[10];
    float* out = (float*)d_out;

    // hx: 0x7F each launch -> u16 0x7F7F has bit14==1: fails the parity-0
    // validator that t=1/t=2 readers use; erases all cross-replay data.
    // No flags to initialize — parity is the only gate.
    hipMemsetAsync(d_ws, 0x7F, HX_BYTES, stream);

    lstm_fused<<<dim3(256), dim3(256), 0, stream>>>(
        x, h0, c0, Wf, Bf, Wi, Bi, Wc, Bc, Wo, Bo, out,
        (unsigned short*)d_ws);
}

// Round 15
// 4891.694 us; speedup vs baseline: 1.7373x; 1.7373x over previous
//
#include <hip/hip_runtime.h>
#include <hip/hip_bf16.h>

// LSTM: L=1024, B=64, I=512, H=512, fp32 in/out.
// Persistent kernel, 256 WGs x 256 thr (1 WG/CU). 8 clusters x 32 WGs;
// cluster = 8 batches; wave = 16 gate rows (4 h-idx x 4 gates). Weights in
// VGPRs as MFMA B-fragments; C state in registers; x-GEMM in-loop.
// ROUND-15 = ROUND-8 CHASSIS (proven 5824us: parity-coded h, advisory
// per-wave flags, cheap 512B flag poll, validated 8KB load) + ONE change:
// OVERLAPPED ISSUE of the h-load with the FIRST flag read. One monolithic
// asm block (16 x global_load_dwordx4 sc0 sc1 + 1 flag dwordx2 + vmcnt(0)
// all inside — round-4 integrity rule) returns both. Cases:
//   flag ready + parity valid  -> data already in regs: ONE RT total
//                                 (round 8 paid detect RT + load RT).
//   flag ready, parity stale   -> one validated reload (== round 8).
//   flag not ready             -> round-8 cheap poll (512B/attempt, sleep-
//                                 paced) then validated reload (== round 8
//                                 + one overlapped wasted load; round 10
//                                 showed this traffic is ~free — its cost
//                                 was SERIALIZING spec before the gate).
// No paced data re-polling anywhere (round-13/14 failure mode): data is
// fetched at most twice per step; stragglers wait on the 512B flag loop.
// Parity code: code = h_bits ^ (((t>>1)&1)?0xFFFF:0); |h|<=1 => bf16
// bit14==0; coded parity-1 => bit14==1. Validator tests bit14 only.
// Slot-reuse induction, 0x7F hx memset, flag memset: as rounds 8/10.

typedef __attribute__((ext_vector_type(8))) short bf16x8;
typedef __attribute__((ext_vector_type(4))) float f32x4;
typedef __attribute__((ext_vector_type(4))) unsigned int u32x4;

#define NT 1024
#define NB 64
#define NH 512
#define NI 512

#define FLAGS_OFF 0        // u32[8][128]  (4 KiB)
#define HX_OFF    4096     // u16[2][64][512] (128 KiB)
#define HX_BYTES  (2 * NB * NH * 2)

#define VBITS   0x4000400040004000ULL   // bit14 of each u16 (u64 view)
#define VBITS32 0x40004000u             // bit14 of each u16 (u32 view)

__device__ __forceinline__ bf16x8 pack8(float4 a, float4 b) {
    union U2 { __hip_bfloat162 h; unsigned int u; } c0, c1, c2, c3;
    c0.h = __float22bfloat162_rn(make_float2(a.x, a.y));
    c1.h = __float22bfloat162_rn(make_float2(a.z, a.w));
    c2.h = __float22bfloat162_rn(make_float2(b.x, b.y));
    c3.h = __float22bfloat162_rn(make_float2(b.z, b.w));
    union R { bf16x8 v; unsigned int u[4]; } r;
    r.u[0] = c0.u; r.u[1] = c1.u; r.u[2] = c2.u; r.u[3] = c3.u;
    return r.v;
}

__device__ __forceinline__ float sigm(float v) {
    return 1.0f / (1.0f + __expf(-v));
}
__device__ __forceinline__ float tanh_f(float v) {
    float e = __expf(-2.0f * fabsf(v));        // in (0,1], no overflow
    float r = (1.0f - e) / (1.0f + e);         // <= 1 in fp32
    return copysignf(r, v);
}

// Monolithic: issue 16 h dwordx4 loads + 1 flag dwordx2, wait all, in ONE
// asm block so the compiler can never spill/reorder into the in-flight window.
__device__ __forceinline__ void spec_load(const void* hp, const void* fp,
                                          u32x4 raw[16],
                                          unsigned long long& fv) {
    asm volatile(
        "global_load_dwordx4 %0, %17, off sc0 sc1\n\t"
        "global_load_dwordx4 %1, %17, off offset:64 sc0 sc1\n\t"
        "global_load_dwordx4 %2, %17, off offset:128 sc0 sc1\n\t"
        "global_load_dwordx4 %3, %17, off offset:192 sc0 sc1\n\t"
        "global_load_dwordx4 %4, %17, off offset:256 sc0 sc1\n\t"
        "global_load_dwordx4 %5, %17, off offset:320 sc0 sc1\n\t"
        "global_load_dwordx4 %6, %17, off offset:384 sc0 sc1\n\t"
        "global_load_dwordx4 %7, %17, off offset:448 sc0 sc1\n\t"
        "global_load_dwordx4 %8, %17, off offset:512 sc0 sc1\n\t"
        "global_load_dwordx4 %9, %17, off offset:576 sc0 sc1\n\t"
        "global_load_dwordx4 %10, %17, off offset:640 sc0 sc1\n\t"
        "global_load_dwordx4 %11, %17, off offset:704 sc0 sc1\n\t"
        "global_load_dwordx4 %12, %17, off offset:768 sc0 sc1\n\t"
        "global_load_dwordx4 %13, %17, off offset:832 sc0 sc1\n\t"
        "global_load_dwordx4 %14, %17, off offset:896 sc0 sc1\n\t"
        "global_load_dwordx4 %15, %17, off offset:960 sc0 sc1\n\t"
        "global_load_dwordx2 %16, %18, off sc0 sc1\n\t"
        "s_waitcnt vmcnt(0)"
        : "=&v"(raw[0]), "=&v"(raw[1]), "=&v"(raw[2]), "=&v"(raw[3]),
          "=&v"(raw[4]), "=&v"(raw[5]), "=&v"(raw[6]), "=&v"(raw[7]),
          "=&v"(raw[8]), "=&v"(raw[9]), "=&v"(raw[10]), "=&v"(raw[11]),
          "=&v"(raw[12]), "=&v"(raw[13]), "=&v"(raw[14]), "=&v"(raw[15]),
          "=&v"(fv)
        : "v"(hp), "v"(fp)
        : "memory");
}

__global__ __launch_bounds__(256, 1) void lstm_fused(
    const float* __restrict__ x,
    const float* __restrict__ h0,
    const float* __restrict__ c0,
    const float* __restrict__ Wf, const float* __restrict__ Bf,
    const float* __restrict__ Wi, const float* __restrict__ Bi,
    const float* __restrict__ Wc, const float* __restrict__ Bc,
    const float* __restrict__ Wo, const float* __restrict__ Bo,
    float* __restrict__ out,
    unsigned char* __restrict__ ws)
{
    unsigned int*   flags = (unsigned int*)(ws + FLAGS_OFF);
    unsigned short* hx    = (unsigned short*)(ws + HX_OFF);

    const int tid  = threadIdx.x;
    const int wv   = tid >> 6;            // wave 0..3
    const int lane = tid & 63;
    const int n    = lane & 15;           // D col (gate row within wave tile)
    const int kg   = lane >> 4;           // k-group 0..3
    const int cl   = blockIdx.x & 7;      // cluster (XCD-swizzle heuristic)
    const int wg   = blockIdx.x >> 3;     // WG within cluster, 0..31

    const int jj = (wv << 2) + (n >> 2);          // 0..15 within WG
    const int j  = (wg << 4) + jj;                // global h index
    const int g  = n & 3;                         // 0=f 1=i 2=c 3=o

    const float* Wg = (g == 0) ? Wf : (g == 1) ? Wi : (g == 2) ? Wc : Wo;
    const float* Bg = (g == 0) ? Bf : (g == 1) ? Bi : (g == 2) ? Bc : Bo;

    const int m_a   = (n < 8) ? n : 7;            // A-row batch (8..15 dup)
    const int bglob = cl * 8 + m_a;

    // ---- prologue: static B-fragments (weights, bf16) into VGPRs ----
    bf16x8 bfrag[32];                             // [0..15]=h-part, [16..31]=x
    {
        const float* wrow = Wg + (size_t)j * (NH + NI);
        #pragma unroll
        for (int kb = 0; kb < 32; ++kb) {
            const float* p = wrow + kb * 32 + kg * 8;
            bfrag[kb] = pack8(*(const float4*)(p), *(const float4*)(p + 4));
        }
    }
    const float bias_v = Bg[j];

    const bool active = (g == 0) && (kg < 2);     // 8 lanes/wave x 4 regs
    float Cst[4];
    #pragma unroll
    for (int r = 0; r < 4; ++r)
        Cst[r] = active ? c0[(size_t)(cl * 8 + kg * 4 + r) * NH + j] : 0.0f;

    unsigned int* fb = flags + cl * 128;          // 128 wave-flags, 512 B
    const int myflag = wg * 4 + wv;

    for (int t = 0; t < NT; ++t) {
        // -- x fragments + x-partial MFMAs (overlap producer lag; pacing) --
        const float* xrow = x + ((size_t)t * NB + bglob) * NI;
        bf16x8 xfrag[16];
        #pragma unroll
        for (int q = 0; q < 16; ++q) {
            const float* p = xrow + q * 32 + kg * 8;
            xfrag[q] = pack8(*(const float4*)(p), *(const float4*)(p + 4));
        }
        f32x4 a0 = {bias_v, bias_v, bias_v, bias_v};
        f32x4 a1 = {0.f, 0.f, 0.f, 0.f};
        f32x4 a2 = {0.f, 0.f, 0.f, 0.f};
        f32x4 a3 = {0.f, 0.f, 0.f, 0.f};
        #pragma unroll
        for (int q = 0; q < 16; q += 4) {
            a0 = __builtin_amdgcn_mfma_f32_16x16x32_bf16(xfrag[q],     bfrag[16 + q],     a0, 0, 0, 0);
            a1 = __builtin_amdgcn_mfma_f32_16x16x32_bf16(xfrag[q + 1], bfrag[16 + q + 1], a1, 0, 0, 0);
            a2 = __builtin_amdgcn_mfma_f32_16x16x32_bf16(xfrag[q + 2], bfrag[16 + q + 2], a2, 0, 0, 0);
            a3 = __builtin_amdgcn_mfma_f32_16x16x32_bf16(xfrag[q + 3], bfrag[16 + q + 3], a3, 0, 0, 0);
        }

        // -- h fragments --
        bf16x8 hfrag[16];
        if (t == 0) {
            const float* hrow = h0 + (size_t)bglob * NH;
            #pragma unroll
            for (int q = 0; q < 16; ++q) {
                const float* p = hrow + q * 32 + kg * 8;
                hfrag[q] = pack8(*(const float4*)(p), *(const float4*)(p + 4));
            }
        } else {
            const unsigned int tgt  = (unsigned int)t;
            const unsigned int pm32 = (((t - 1) >> 1) & 1) ? 0xFFFFFFFFu : 0u;
            const unsigned long long pm64 =
                (((t - 1) >> 1) & 1) ? ~0ULL : 0ULL;
            const unsigned short* hrow =
                hx + ((size_t)((t - 1) & 1) * NB + bglob) * NH;
            const void* hp = (const char*)hrow + kg * 16;
            const void* fp = (const void*)((const unsigned long long*)fb + lane);

            // (1) overlapped issue: h data + first flag read, one RT
            u32x4 raw[16];
            unsigned long long fv;
            spec_load(hp, fp, raw, fv);
            bool fok = ((unsigned int)fv >= tgt) &&
                       ((unsigned int)(fv >> 32) >= tgt);

            // (2) straggler path: cheap 512B flag poll (round-8 exact)
            if (!__all(fok)) {
                int guard = 1 << 20;
                for (;;) {
                    unsigned long long f2 = __hip_atomic_load(
                        (const unsigned long long*)fp,
                        __ATOMIC_RELAXED, __HIP_MEMORY_SCOPE_AGENT);
                    bool ok = ((unsigned int)f2 >= tgt) &&
                              ((unsigned int)(f2 >> 32) >= tgt);
                    if (__all(ok)) break;
                    if (--guard == 0) break;      // hang safety
                    __builtin_amdgcn_s_sleep(1);
                }
            }
            __builtin_amdgcn_sched_barrier(0);

            // (3) parity-validate the speculative data
            u32x4 pmv = {pm32, pm32, pm32, pm32};
            u32x4 accv = {0u, 0u, 0u, 0u};
            #pragma unroll
            for (int q = 0; q < 16; ++q) {
                raw[q] ^= pmv;
                accv |= raw[q];
                hfrag[q] = __builtin_bit_cast(bf16x8, raw[q]);
            }
            unsigned int accs = accv.x | accv.y | accv.z | accv.w;
            if (!__all((accs & VBITS32) == 0u)) {
                // (4) stale race sliver: one validated reload (round-8 exact)
                int guard = 1 << 16;
                for (;;) {
                    unsigned long long accb = 0;
                    #pragma unroll
                    for (int q = 0; q < 16; ++q) {
                        const unsigned long long* p =
                            (const unsigned long long*)(hrow + q * 32 + kg * 8);
                        union { bf16x8 v; unsigned long long u[2]; } un;
                        unsigned long long w0 = __hip_atomic_load(
                            p, __ATOMIC_RELAXED, __HIP_MEMORY_SCOPE_AGENT) ^ pm64;
                        unsigned long long w1 = __hip_atomic_load(
                            p + 1, __ATOMIC_RELAXED, __HIP_MEMORY_SCOPE_AGENT) ^ pm64;
                        accb |= w0;
                        accb |= w1;
                        un.u[0] = w0;
                        un.u[1] = w1;
                        hfrag[q] = un.v;
                    }
                    if (__all((accb & VBITS) == 0ULL)) break;
                    if (--guard == 0) break;      // hang safety
                }
            }
            __builtin_amdgcn_sched_barrier(0);
        }

        #pragma unroll
        for (int q = 0; q < 16; q += 4) {
            a0 = __builtin_amdgcn_mfma_f32_16x16x32_bf16(hfrag[q],     bfrag[q],     a0, 0, 0, 0);
            a1 = __builtin_amdgcn_mfma_f32_16x16x32_bf16(hfrag[q + 1], bfrag[q + 1], a1, 0, 0, 0);
            a2 = __builtin_amdgcn_mfma_f32_16x16x32_bf16(hfrag[q + 2], bfrag[q + 2], a2, 0, 0, 0);
            a3 = __builtin_amdgcn_mfma_f32_16x16x32_bf16(hfrag[q + 3], bfrag[q + 3], a3, 0, 0, 0);
        }
        f32x4 acc = (a0 + a1) + (a2 + a3);

        // -- gather f/i/c/o in 4-lane groups, elementwise, coded h-store --
        unsigned short* hxout = hx + (size_t)(t & 1) * NB * NH;
        const unsigned int pmask = ((t >> 1) & 1) ? 0xFFFFu : 0u;
        float harr[4];
        #pragma unroll
        for (int r = 0; r < 4; ++r) {
            float fv = acc[r];
            float iv = __shfl_xor(fv, 1);
            float gv = __shfl_xor(fv, 2);
            float ov = __shfl_xor(fv, 3);
            if (active) {
                float ft = sigm(fv);
                float it = sigm(iv);
                float gt = tanh_f(gv);
                float ot = sigm(ov);
                float Cn = ft * Cst[r] + it * gt;
                Cst[r] = Cn;
                float ht = ot * tanh_f(Cn);       // |ht| <= 1.0 in fp32
                harr[r] = ht;
                int m = kg * 4 + r;               // batch within cluster
                __hip_bfloat16 hb = __float2bfloat16(ht);
                unsigned short code =
                    (unsigned short)((*(unsigned short*)&hb) ^ pmask);
                __hip_atomic_store(
                    (unsigned short*)(hxout + (size_t)(cl * 8 + m) * NH + j),
                    code, __ATOMIC_RELAXED, __HIP_MEMORY_SCOPE_AGENT);
            }
        }

        // -- advisory flag: NO drain (parity is the real gate) --
        __builtin_amdgcn_sched_barrier(0);        // keep flag after h-stores
        if (lane == 0)
            __hip_atomic_store(fb + myflag, (unsigned int)(t + 1),
                               __ATOMIC_RELAXED, __HIP_MEMORY_SCOPE_AGENT);

        // -- fp32 output stores AFTER publish (off the critical path) --
        if (active) {
            #pragma unroll
            for (int r = 0; r < 4; ++r) {
                int m = kg * 4 + r;
                out[((size_t)t * NB + cl * 8 + m) * NH + j] = harr[r];
            }
        }
    }
}

extern "C" void kernel_launch(void* const* d_in, const int* in_sizes, int n_in,
                              void* d_out, int out_size, void* d_ws, size_t ws_size,
                              hipStream_t stream) {
    const float* x  = (const float*)d_in[0];
    const float* h0 = (const float*)d_in[1];
    const float* c0 = (const float*)d_in[2];
    const float* Wf = (const float*)d_in[3];
    const float* Bf = (const float*)d_in[4];
    const float* Wi = (const float*)d_in[5];
    const float* Bi = (const float*)d_in[6];
    const float* Wc = (const float*)d_in[7];
    const float* Bc = (const float*)d_in[8];
    const float* Wo = (const float*)d_in[9];
    const float* Bo = (const float*)d_in[10];
    float* out = (float*)d_out;

    // Flags: zero each launch (monotonic, must restart).
    hipMemsetAsync(d_ws, 0, 4096, stream);
    // hx: 0x7F each launch -> u16 0x7F7F has bit14==1: fails the parity-0
    // validator used by t=1/t=2 readers; erases all cross-replay data.
    hipMemsetAsync((char*)d_ws + HX_OFF, 0x7F, HX_BYTES, stream);

    lstm_fused<<<dim3(256), dim3(256), 0, stream>>>(
        x, h0, c0, Wf, Bf, Wi, Bi, Wc, Bc, Wo, Bo, out,
        (unsigned char*)d_ws);
}